// Round 10
// baseline (537.609 us; speedup 1.0000x reference)
//
#include <hip/hip_runtime.h>
#include <hip/hip_bf16.h>

#define H_DIM 2048
#define E_NUM 8
#define I_DIM 4096
#define TWO_I 8192
#define T_TOK 2048

#define BM 128
#define BN 64
#define BK 64

typedef __bf16 bf16x8 __attribute__((ext_vector_type(8)));
typedef float f32x4 __attribute__((ext_vector_type(4)));

static __device__ __forceinline__ unsigned short f2bs(float x) {
    __hip_bfloat16 h = __float2bfloat16(x);
    return __builtin_bit_cast(unsigned short, h);
}

#define GLL(gsrc, ldst) __builtin_amdgcn_global_load_lds( \
    (const __attribute__((address_space(1))) void*)(gsrc), \
    (__attribute__((address_space(3))) void*)(ldst), 16, 0, 0)

#define MFMA16(a, b, c) __builtin_amdgcn_mfma_f32_16x16x32_bf16(a, b, c, 0, 0, 0)
#define BSWZ(n) (((((n) & 7) ^ (((n) >> 2) & 7))) << 4)
#define A_SRC_CHUNK(lane) ((((lane) & 7) ^ (((lane) >> 3) & 7)) * 8)
// barrier WITHOUT vmcnt drain: LDS writes visible; global/GLL loads stay in flight
#define BARRIER() asm volatile("s_waitcnt lgkmcnt(0)\ns_barrier" ::: "memory")

static __device__ __forceinline__ bf16x8 bload(
    const unsigned short* __restrict__ Bs, int n, int s, int h) {
    int off = (n * 128 + s * 64 + h * 16) ^ BSWZ(n);
    return *reinterpret_cast<const bf16x8*>((const char*)Bs + off);
}

static __device__ __forceinline__ bf16x8 aload(
    const unsigned short* __restrict__ As, int row, int s, int h) {
    int off = row * 128 + ((s * 64 + h * 16) ^ ((row & 7) << 4));
    return *reinterpret_cast<const bf16x8*>((const char*)As + off);
}

// ---------------- fused router + convert: one wave per token ----------------
__global__ __launch_bounds__(256) void router_convert_kernel(
    const float* __restrict__ hs, const float* __restrict__ rw,
    float* __restrict__ out_scores, int* __restrict__ eidx,
    unsigned short* __restrict__ xb, unsigned short* __restrict__ xs) {
    int tok = blockIdx.x * 4 + (threadIdx.x >> 6);
    int lane = threadIdx.x & 63;
    const float* row = hs + (size_t)tok * H_DIM;
    float4 v[8];
    float acc[E_NUM];
#pragma unroll
    for (int e = 0; e < E_NUM; e++) acc[e] = 0.f;
#pragma unroll
    for (int i = 0; i < 8; i++) {
        int hb = i * 256 + lane * 4;
        v[i] = *reinterpret_cast<const float4*>(row + hb);
        const float* w0 = rw + (size_t)hb * E_NUM;
#pragma unroll
        for (int e = 0; e < E_NUM; e++) {
            acc[e] += v[i].x * w0[e] + v[i].y * w0[E_NUM + e] +
                      v[i].z * w0[2 * E_NUM + e] + v[i].w * w0[3 * E_NUM + e];
        }
    }
#pragma unroll
    for (int e = 0; e < E_NUM; e++) {
#pragma unroll
        for (int o = 32; o > 0; o >>= 1) acc[e] += __shfl_xor(acc[e], o, 64);
    }
    int best = 0; float bv = acc[0];
#pragma unroll
    for (int e = 1; e < E_NUM; e++) { if (acc[e] > bv) { bv = acc[e]; best = e; } }
    float sc = 1.f / (1.f + expf(-bv));
    if (lane < E_NUM) out_scores[(size_t)lane * T_TOK + tok] = (lane == best) ? sc : 0.f;
    if (lane == 0) eidx[tok] = best;
    unsigned short* xbr = xb + (size_t)tok * H_DIM;
    unsigned short* xsr = xs + (size_t)tok * H_DIM;
#pragma unroll
    for (int i = 0; i < 8; i++) {
        int hb = i * 256 + lane * 4;
        ushort4 b, s4;
        b.x = f2bs(v[i].x); b.y = f2bs(v[i].y); b.z = f2bs(v[i].z); b.w = f2bs(v[i].w);
        s4.x = f2bs(v[i].x * sc); s4.y = f2bs(v[i].y * sc);
        s4.z = f2bs(v[i].z * sc); s4.w = f2bs(v[i].w * sc);
        *reinterpret_cast<ushort4*>(xbr + hb) = b;
        *reinterpret_cast<ushort4*>(xsr + hb) = s4;
    }
}

// ---------------- grouping ----------------
__global__ void group_kernel(const int* __restrict__ eidx, int* __restrict__ perm,
                             int* __restrict__ off) {
    __shared__ int cnt[E_NUM];
    __shared__ int base[E_NUM];
    int t = threadIdx.x;
    if (t < E_NUM) cnt[t] = 0;
    __syncthreads();
    for (int i = t; i < T_TOK; i += 256) atomicAdd(&cnt[eidx[i]], 1);
    __syncthreads();
    if (t == 0) {
        int s = 0;
        for (int e = 0; e < E_NUM; e++) { base[e] = s; off[e] = s; s += cnt[e]; }
        off[E_NUM] = s;
    }
    __syncthreads();
    for (int i = t; i < T_TOK; i += 256) {
        int e = eidx[i];
        int p = atomicAdd(&base[e], 1);
        perm[p] = i;
    }
}

// ---------------- GEMM1: R9 schedule, BM=128, 3 blocks/CU ----------------
// 256 thr, BM=128, BN=64 gate + 64 up, BK=64. As dbuf (GLL), B single-buf reg-staged.
// grid.x = I/64, grid.y = g*16 + mt
__global__ __launch_bounds__(256, 3) void gemm1_kernel(
    const unsigned short* __restrict__ xb, const unsigned short* __restrict__ xs,
    const float* __restrict__ gup, const float* __restrict__ sg,
    const float* __restrict__ su, const int* __restrict__ perm,
    const int* __restrict__ off, unsigned short* __restrict__ hmid) {
    int nt = blockIdx.x;
    int g = blockIdx.y >> 4;
    int mt = blockIdx.y & 15;
    int rowbase, ng;
    if (g < E_NUM) { rowbase = off[g]; ng = off[g + 1] - rowbase; }
    else { rowbase = 0; ng = T_TOK; }
    int mstart = mt * BM;
    if (mstart >= ng) return;

    __shared__ unsigned short As[2][BM * BK];  // 2 x 16 KB
    __shared__ unsigned short Bg[BN * BK];     // 8 KB
    __shared__ unsigned short Bu[BN * BK];     // 8 KB

    int tid = threadIdx.x;
    int wave = tid >> 6, lane = tid & 63;
    int h = lane >> 4, ln = lane & 15;

    const unsigned short* Abase = (g == E_NUM) ? xb : xs;
    unsigned int aoff[4];
#pragma unroll
    for (int j = 0; j < 4; j++) {
        int r = wave * 32 + j * 8 + (lane >> 3);
        int sr = mstart + r; sr = (sr < ng) ? sr : (ng - 1);
        int tokr = (g < E_NUM) ? perm[rowbase + sr] : sr;
        aoff[j] = (unsigned int)tokr * H_DIM + A_SRC_CHUNK(lane);
    }
    int n0 = nt * BN;
    const float* gbase;
    const float* ubase;
    size_t ldb;
    if (g < E_NUM) {
        gbase = gup + (size_t)g * H_DIM * TWO_I + n0;
        ubase = gbase + I_DIM;
        ldb = TWO_I;
    } else {
        gbase = sg + n0;
        ubase = su + n0;
        ldb = I_DIM;
    }
    int k0i = wave * 16 + ((lane >> 4) << 2);  // 4 k-rows per lane
    int nb = (lane & 15) << 2;                 // 4 n-cols per lane
    const float* pg = gbase + (size_t)k0i * ldb + nb;
    const float* pu = ubase + (size_t)k0i * ldb + nb;

    f32x4 zero = {0.f, 0.f, 0.f, 0.f};
    f32x4 accg[2][4], accu[2][4];
#pragma unroll
    for (int i = 0; i < 2; i++)
#pragma unroll
        for (int j = 0; j < 4; j++) { accg[i][j] = zero; accu[i][j] = zero; }

    const int NT = H_DIM / BK;   // 32
    f32x4 qg0, qg1, qg2, qg3, qu0, qu1, qu2, qu3;

#define G1_QLOAD(t_) { size_t ko_ = (size_t)(t_) * BK * ldb; \
        const float* p_ = pg + ko_; \
        qg0 = *reinterpret_cast<const f32x4*>(p_); \
        qg1 = *reinterpret_cast<const f32x4*>(p_ + ldb); \
        qg2 = *reinterpret_cast<const f32x4*>(p_ + 2 * ldb); \
        qg3 = *reinterpret_cast<const f32x4*>(p_ + 3 * ldb); \
        p_ = pu + ko_; \
        qu0 = *reinterpret_cast<const f32x4*>(p_); \
        qu1 = *reinterpret_cast<const f32x4*>(p_ + ldb); \
        qu2 = *reinterpret_cast<const f32x4*>(p_ + 2 * ldb); \
        qu3 = *reinterpret_cast<const f32x4*>(p_ + 3 * ldb); }
#define G1_BWRITE() { _Pragma("unroll") \
        for (int i_ = 0; i_ < 4; i_++) { int n_ = nb + i_; \
            ushort4 og_, ou_; \
            og_.x = f2bs(qg0[i_]); og_.y = f2bs(qg1[i_]); \
            og_.z = f2bs(qg2[i_]); og_.w = f2bs(qg3[i_]); \
            ou_.x = f2bs(qu0[i_]); ou_.y = f2bs(qu1[i_]); \
            ou_.z = f2bs(qu2[i_]); ou_.w = f2bs(qu3[i_]); \
            int ob_ = (n_ * 128 + k0i * 2) ^ BSWZ(n_); \
            *reinterpret_cast<ushort4*>((char*)Bg + ob_) = og_; \
            *reinterpret_cast<ushort4*>((char*)Bu + ob_) = ou_; } }
#define G1_AGLL(t_, buf_) { _Pragma("unroll") \
        for (int j_ = 0; j_ < 4; j_++) \
            GLL(Abase + aoff[j_] + (unsigned)(t_) * BK, \
                &As[buf_][(wave * 32 + j_ * 8) * BK]); }

    // prologue: B(0)->LDS, A(0)->As[0], A(1)->As[1], B(1)->regs
    G1_QLOAD(0);
    G1_AGLL(0, 0);
    asm volatile("s_waitcnt vmcnt(0)" ::: "memory");
    G1_BWRITE();
    G1_AGLL(1, 1);
    G1_QLOAD(1);
    BARRIER();

    for (int t = 0; t < NT; ++t) {
        const unsigned short* Ab = &As[t & 1][0];
#pragma unroll
        for (int s = 0; s < 2; s++) {
            bf16x8 a0 = aload(Ab, wave * 32 + 0 * 16 + ln, s, h);
            bf16x8 a1 = aload(Ab, wave * 32 + 1 * 16 + ln, s, h);
#pragma unroll
            for (int j = 0; j < 4; j++) {
                bf16x8 bg = bload(Bg, j * 16 + ln, s, h);
                accg[0][j] = MFMA16(a0, bg, accg[0][j]);
                accg[1][j] = MFMA16(a1, bg, accg[1][j]);
            }
#pragma unroll
            for (int j = 0; j < 4; j++) {
                bf16x8 bu = bload(Bu, j * 16 + ln, s, h);
                accu[0][j] = MFMA16(a0, bu, accu[0][j]);
                accu[1][j] = MFMA16(a1, bu, accu[1][j]);
            }
        }
        BARRIER();                       // reads of As[t&1], B(t) done
        if (t + 1 < NT) {
            G1_BWRITE();                 // B(t+1); implicit counted vmcnt here only
            int tc = t + 2; if (tc > NT - 1) tc = NT - 1;
            G1_AGLL(tc, t & 1);          // A(t+2) into the buffer just read
            G1_QLOAD(tc);                // B(t+2) -> regs, stays in flight
            BARRIER();                   // B(t+1) visible; loads NOT drained
        }
    }

    int hbase = (g < E_NUM) ? rowbase : T_TOK;
#pragma unroll
    for (int i = 0; i < 2; i++) {
#pragma unroll
        for (int j = 0; j < 4; j++) {
#pragma unroll
            for (int r = 0; r < 4; r++) {
                int row = wave * 32 + i * 16 + h * 4 + r;
                int sr = mstart + row;
                if (sr < ng) {
                    float gv = accg[i][j][r], uv = accu[i][j][r];
                    float hv = gv / (1.f + expf(-gv)) * uv;  // silu(g)*u
                    int col = n0 + j * 16 + ln;
                    hmid[(size_t)(hbase + sr) * I_DIM + col] = f2bs(hv);
                }
            }
        }
    }
}

// ---------------- GEMM2: down proj, same pipeline, BM=128, 4 blocks/CU ----------------
// 256 thr, BM=128, BN=64, BK=64. grid.x = H/64. ADD=0: grid.y=mt(0..15); ADD=1: g*16+mt
template <int ADD>
__global__ __launch_bounds__(256, 4) void gemm2_kernel(
    const unsigned short* __restrict__ hmid, const float* __restrict__ dwn,
    const float* __restrict__ sd, const int* __restrict__ perm,
    const int* __restrict__ off, float* __restrict__ out) {
    int nt = blockIdx.x;
    int g, mt, rowbase, ng, hbase;
    if (ADD) {
        g = blockIdx.y >> 4; mt = blockIdx.y & 15;
        rowbase = off[g]; ng = off[g + 1] - rowbase; hbase = rowbase;
    } else {
        g = E_NUM; mt = blockIdx.y; rowbase = 0; ng = T_TOK; hbase = T_TOK;
    }
    int mstart = mt * BM;
    if (mstart >= ng) return;

    __shared__ unsigned short As[2][BM * BK];  // 2 x 16 KB
    __shared__ unsigned short Bs[BN * BK];     // 8 KB

    int tid = threadIdx.x;
    int wave = tid >> 6, lane = tid & 63;
    int h = lane >> 4, ln = lane & 15;

    unsigned int aoff[4];
#pragma unroll
    for (int j = 0; j < 4; j++) {
        int r = wave * 32 + j * 8 + (lane >> 3);
        int sr = mstart + r; sr = (sr < ng) ? sr : (ng - 1);
        aoff[j] = (unsigned int)(hbase + sr) * I_DIM + A_SRC_CHUNK(lane);
    }
    int n0 = nt * BN;
    const float* bbase = ADD ? (dwn + (size_t)g * I_DIM * H_DIM + n0) : (sd + n0);
    const size_t ldb = H_DIM;
    int k0i = wave * 16 + ((lane >> 4) << 2);
    int nb = (lane & 15) << 2;
    const float* pb = bbase + (size_t)k0i * ldb + nb;

    f32x4 zero = {0.f, 0.f, 0.f, 0.f};
    f32x4 acc[2][4];
#pragma unroll
    for (int i = 0; i < 2; i++)
#pragma unroll
        for (int j = 0; j < 4; j++) acc[i][j] = zero;

    const int NT2 = I_DIM / BK;  // 64
    f32x4 qb0, qb1, qb2, qb3;

#define G2_QLOAD(t_) { size_t ko_ = (size_t)(t_) * BK * ldb; \
        const float* p_ = pb + ko_; \
        qb0 = *reinterpret_cast<const f32x4*>(p_); \
        qb1 = *reinterpret_cast<const f32x4*>(p_ + ldb); \
        qb2 = *reinterpret_cast<const f32x4*>(p_ + 2 * ldb); \
        qb3 = *reinterpret_cast<const f32x4*>(p_ + 3 * ldb); }
#define G2_BWRITE() { _Pragma("unroll") \
        for (int i_ = 0; i_ < 4; i_++) { int n_ = nb + i_; \
            ushort4 o_; \
            o_.x = f2bs(qb0[i_]); o_.y = f2bs(qb1[i_]); \
            o_.z = f2bs(qb2[i_]); o_.w = f2bs(qb3[i_]); \
            int ob_ = (n_ * 128 + k0i * 2) ^ BSWZ(n_); \
            *reinterpret_cast<ushort4*>((char*)Bs + ob_) = o_; } }
#define G2_AGLL(t_, buf_) { _Pragma("unroll") \
        for (int j_ = 0; j_ < 4; j_++) \
            GLL(hmid + aoff[j_] + (unsigned)(t_) * BK, \
                &As[buf_][(wave * 32 + j_ * 8) * BK]); }

    G2_QLOAD(0);
    G2_AGLL(0, 0);
    asm volatile("s_waitcnt vmcnt(0)" ::: "memory");
    G2_BWRITE();
    G2_AGLL(1, 1);
    G2_QLOAD(1);
    BARRIER();

    for (int t = 0; t < NT2; ++t) {
        const unsigned short* Ab = &As[t & 1][0];
#pragma unroll
        for (int s = 0; s < 2; s++) {
            bf16x8 a0 = aload(Ab, wave * 32 + 0 * 16 + ln, s, h);
            bf16x8 a1 = aload(Ab, wave * 32 + 1 * 16 + ln, s, h);
#pragma unroll
            for (int j = 0; j < 4; j++) {
                bf16x8 b = bload(Bs, j * 16 + ln, s, h);
                acc[0][j] = MFMA16(a0, b, acc[0][j]);
                acc[1][j] = MFMA16(a1, b, acc[1][j]);
            }
        }
        BARRIER();
        if (t + 1 < NT2) {
            G2_BWRITE();
            int tc = t + 2; if (tc > NT2 - 1) tc = NT2 - 1;
            G2_AGLL(tc, t & 1);
            G2_QLOAD(tc);
            BARRIER();
        }
    }

#pragma unroll
    for (int i = 0; i < 2; i++) {
#pragma unroll
        for (int j = 0; j < 4; j++) {
#pragma unroll
            for (int r = 0; r < 4; r++) {
                int row = wave * 32 + i * 16 + h * 4 + r;
                int sr = mstart + row;
                if (sr < ng) {
                    int tok = ADD ? perm[rowbase + sr] : sr;
                    int col = n0 + j * 16 + ln;
                    float v = acc[i][j][r];
                    float* o = out + (size_t)tok * H_DIM + col;
                    if (ADD) *o += v; else *o = v;
                }
            }
        }
    }
}

extern "C" void kernel_launch(void* const* d_in, const int* in_sizes, int n_in,
                              void* d_out, int out_size, void* d_ws, size_t ws_size,
                              hipStream_t stream) {
    (void)in_sizes; (void)n_in; (void)out_size;
    const float* hs  = (const float*)d_in[0];
    const float* rw  = (const float*)d_in[1];
    const float* gup = (const float*)d_in[2];
    const float* dwn = (const float*)d_in[3];
    const float* sg  = (const float*)d_in[4];
    const float* su  = (const float*)d_in[5];
    const float* sd  = (const float*)d_in[6];
    float* out = (float*)d_out;
    float* out_scores = out + (size_t)T_TOK * H_DIM;

    char* w = (char*)d_ws;
    size_t o = 0;
    auto alloc = [&](size_t bytes) {
        void* p = w + o;
        o += (bytes + 255) & ~(size_t)255;
        return p;
    };
    unsigned short* xb   = (unsigned short*)alloc((size_t)T_TOK * H_DIM * 2);
    unsigned short* xs   = (unsigned short*)alloc((size_t)T_TOK * H_DIM * 2);
    unsigned short* hmid = (unsigned short*)alloc((size_t)2 * T_TOK * I_DIM * 2);
    int* eidx    = (int*)alloc(T_TOK * 4);
    int* perm    = (int*)alloc(T_TOK * 4);
    int* off     = (int*)alloc(64 * 4);
    if (ws_size < o) return;  // insufficient workspace

    router_convert_kernel<<<T_TOK / 4, 256, 0, stream>>>(hs, rw, out_scores, eidx, xb, xs);
    group_kernel<<<1, 256, 0, stream>>>(eidx, perm, off);

    gemm1_kernel<<<dim3(I_DIM / BN, 9 * 16), 256, 0, stream>>>(
        xb, xs, gup, sg, su, perm, off, hmid);
    gemm2_kernel<0><<<dim3(H_DIM / BN, 16), 256, 0, stream>>>(hmid, dwn, sd, perm, off, out);
    gemm2_kernel<1><<<dim3(H_DIM / BN, E_NUM * 16), 256, 0, stream>>>(hmid, dwn, sd, perm, off, out);
}